// Round 10
// baseline (29.626 us; speedup 1.0000x reference)
//
#include <hip/hip_runtime.h>
#include <math.h>

// LightweightConv1dTBC: out[t,b,c] = sum_k x[t-15+k, b, c] * softmax(w[h(c),:])[k] + bias[c]
// T=2048 B=8 C=1024 H=16 K=31 P=15, R = C/H = 64 channels per head.
//
// R9: x2-wide (512B/wave-instr granules for BOTH the load stream and the NT
// store stream). R8 showed latency is hidden; the 2x gap to the 6.7 TB/s
// memset (1KB granules) is granularity. Regs: 32 acc + 31 w + pipe ~ 90 <=
// 128 budget from amdgpu_waves_per_eu(2,4) (the only hint that works: R6
// proof). Weights per-lane from LDS table, WPAD=33 to kill R6's bank
// conflicts. Halo stays 2.875x, 8192 waves.

#define T_DIM 2048
#define B_DIM 8
#define C_DIM 1024
#define H_DIM 16
#define K_DIM 31
#define P_PAD 15
#define STRIP 16
#define WPAD 33

typedef float f32x2 __attribute__((ext_vector_type(2)));

template<bool CHECK>
__device__ __forceinline__ void run_strip2(const float* __restrict__ xb,
                                           float* __restrict__ ob,
                                           const float (&w)[K_DIM],
                                           const f32x2 bv, int t0)
{
    f32x2 acc[STRIP];
    #pragma unroll
    for (int i = 0; i < STRIP; ++i) acc[i] = bv;

    #pragma unroll
    for (int r = 0; r < STRIP + K_DIM - 1; ++r) {   // 46 streamed x2 rows
        const int t = t0 - P_PAD + r;
        f32x2 xv = (f32x2)(0.f);
        if (!CHECK || ((unsigned)t < (unsigned)T_DIM)) {
            xv = *reinterpret_cast<const f32x2*>(&xb[(size_t)t * (B_DIM * C_DIM)]);
        }
        #pragma unroll
        for (int i = 0; i < STRIP; ++i) {
            const int k = r - i;
            if (k >= 0 && k < K_DIM) {              // folds statically
                acc[i][0] = fmaf(xv[0], w[k], acc[i][0]);
                acc[i][1] = fmaf(xv[1], w[k], acc[i][1]);
            }
        }
    }

    #pragma unroll
    for (int i = 0; i < STRIP; ++i) {
        __builtin_nontemporal_store(
            acc[i], reinterpret_cast<f32x2*>(&ob[(size_t)(t0 + i) * (B_DIM * C_DIM)]));
    }
}

__global__ __launch_bounds__(256)
__attribute__((amdgpu_waves_per_eu(2, 4)))
void lwconv_tbc_kernel(
    const float* __restrict__ x,       // (T, B, C)
    const float* __restrict__ weight,  // (H, 1, K)
    const float* __restrict__ bias,    // (C,)
    float* __restrict__ out)           // (T, B, C)
{
    __shared__ float s_w[H_DIM][WPAD];  // softmaxed weight table (WPAD=33: no bank conflicts)

    const int tid = threadIdx.x;

    // --- per-block softmax: threads 0..15 each handle one head (tiny) ---
    if (tid < H_DIM) {
        float wv[K_DIM];
        float m = -1e30f;
        for (int k = 0; k < K_DIM; ++k) {
            wv[k] = weight[tid * K_DIM + k];
            m = fmaxf(m, wv[k]);
        }
        float s = 0.f;
        for (int k = 0; k < K_DIM; ++k) { wv[k] = expf(wv[k] - m); s += wv[k]; }
        const float inv = 1.f / s;
        for (int k = 0; k < K_DIM; ++k) s_w[tid][k] = wv[k] * inv;
    }
    __syncthreads();

    const int c  = blockIdx.x * 512 + tid * 2;   // block covers 512 channels
    const int h  = c >> 6;
    const int b  = blockIdx.y;
    const int t0 = blockIdx.z * STRIP;

    // head weights -> per-lane VGPRs (broadcast within 32-lane groups)
    float w[K_DIM];
    #pragma unroll
    for (int k = 0; k < K_DIM; ++k) w[k] = s_w[h][k];

    const f32x2 bv = *reinterpret_cast<const f32x2*>(&bias[c]);
    const float* xb = x + (size_t)b * C_DIM + c;
    float* ob = out + (size_t)b * C_DIM + c;

    // interior strips need rows t0-15 .. t0+STRIP-1+15 all in [0, T)
    const bool interior = (t0 >= P_PAD) && (t0 + STRIP - 1 + K_DIM - 1 - P_PAD < T_DIM);
    if (interior) run_strip2<false>(xb, ob, w, bv, t0);
    else          run_strip2<true >(xb, ob, w, bv, t0);
}

extern "C" void kernel_launch(void* const* d_in, const int* in_sizes, int n_in,
                              void* d_out, int out_size, void* d_ws, size_t ws_size,
                              hipStream_t stream) {
    const float* x      = (const float*)d_in[0];
    const float* weight = (const float*)d_in[1];
    const float* bias   = (const float*)d_in[2];
    float* out = (float*)d_out;

    dim3 grid(C_DIM / 512, B_DIM, T_DIM / STRIP);   // (2, 8, 128) = 2048 blocks
    dim3 block(256);
    lwconv_tbc_kernel<<<grid, block, 0, stream>>>(x, weight, bias, out);
}